// Round 6
// baseline (283.390 us; speedup 1.0000x reference)
//
#include <hip/hip_runtime.h>

// DMoE (PLE/CGC) fused kernel for MI355X (gfx950).
// B=32768, D_IN=256, H=128, N_TASK=2, N_EXP=4, N_SHARE=4.
//
// R13: K-split wave-pair version of R12. R12 (weights fully resident, 488
// regs, 1 wave/SIMD) proved resident weights kill all staging traffic but
// 1 wave/SIMD exposes every latency (7.9K cyc/tile vs ~400 issue) -> 105us.
// Fix: minimum viable residency per wave = 128 AGPR (half-K of all 8 slots),
// 2 waves/SIMD:
//  - 128-thr blocks (2 waves). Wave u holds k in [128u,128u+128) fragments
//    of all 8 experts (8 slots x 4 ks, pinned AGPR) + gate-half + its x half.
//  - per 16-row tile: 36 MFMAs/wave (9 interleaved chains), then partial-acc
//    exchange via 18KB dbuf LDS, ONE __syncthreads/tile, combiner role
//    alternates per tile (self-balancing pipeline).
//  - ~252 unified regs/wave -> __launch_bounds__(128,2): 2 waves/SIMD,
//    4 blocks/CU, grid 1024 exactly co-resident. t = blk&1 keeps task/XCD
//    affinity; 16 consecutive blocks share the same x rows (L3 locality).
// prep_kernel verbatim R12 (fragment image, proven).

typedef __attribute__((ext_vector_type(8))) short short8;   // 8 x bf16
typedef __attribute__((ext_vector_type(4))) float float4v;  // MFMA C/D

#define WF_GOFF_US 393216     // 12 experts * 8 h16 * 8 kk * 512 us
#define WS_NEED_B  802816     // + 16*256 gate ushorts

__device__ __forceinline__ unsigned short f2bf(float f) {
  unsigned u = __builtin_bit_cast(unsigned, f);
  u += 0x7FFFu + ((u >> 16) & 1u);   // round-to-nearest-even
  return (unsigned short)(u >> 16);
}

__device__ __forceinline__ int slot2e(int sr, int t) {
  return (sr < 4) ? sr : 4 + t * 4 + (sr - 4);
}

// ---------------------------------------------------------------------------
// Prep: WF[e(12)][h16(8)][kk(8)][lane(64)][8 bf16] fragment image + WgT[16][256].
// Element (e,h16,kk,lane=quad*16+col,j) = W_e[kk*32+quad*8+j][h16*16+col].
// (verbatim R12 - proven)
__global__ __launch_bounds__(256)
void prep_kernel(const float* __restrict__ Ws,
                 const float* __restrict__ Wt,
                 const float* __restrict__ Wg,
                 unsigned short* __restrict__ WT) {
  int bid = blockIdx.x;
  int tid = threadIdx.x;
  if (bid < 96) {
    int e = bid >> 3, h16 = bid & 7;
    const float* src = (e < 4) ? Ws + ((size_t)e << 15)
                               : Wt + ((size_t)(e - 4) << 15);
    int k = tid;                       // one thread per k-row
    int kk = k >> 5, quad = (k >> 3) & 3, j = k & 7;
    size_t eb = ((size_t)(e * 8 + h16) * 8 + kk) * 512 + (size_t)quad * 128 + j;
    const float* sp = src + (size_t)k * 128 + h16 * 16;
    #pragma unroll
    for (int c4 = 0; c4 < 4; ++c4) {
      float4 v = *(const float4*)(sp + c4 * 4);
      WT[eb + (size_t)(c4 * 4 + 0) * 8] = f2bf(v.x);
      WT[eb + (size_t)(c4 * 4 + 1) * 8] = f2bf(v.y);
      WT[eb + (size_t)(c4 * 4 + 2) * 8] = f2bf(v.z);
      WT[eb + (size_t)(c4 * 4 + 3) * 8] = f2bf(v.w);
    }
  } else {
    // gate weights WgT[n][256], n = t*8+g
    #pragma unroll
    for (int it = 0; it < 16; ++it) {
      int jj = it * 256 + tid;
      int n = jj >> 8, k = jj & 255;
      int tt = n >> 3, g = n & 7;
      WT[WF_GOFF_US + jj] = f2bf(Wg[(size_t)(tt * 256 + k) * 8 + g]);
    }
  }
}

// ---------------------------------------------------------------------------
__global__ __launch_bounds__(128, 2)
void dmoe_main(const float* __restrict__ x,
               const unsigned short* __restrict__ WT,
               const float* __restrict__ b_share,
               const float* __restrict__ b_task,
               const float* __restrict__ b_gate,
               float* __restrict__ out) {
  __shared__ float exch[2][9][64][4];  // partial acc exchange, dbuf (18432 B)
  __shared__ float gw[2][8][20];       // gates [slot][16 rows]+pad (combiner)
  __shared__ float biasL[8][16];       // [slot][col]

  const int tid  = threadIdx.x;
  const int lane = tid & 63;
  const int w    = tid >> 6;           // wave 0..1 = K-half
  const int col  = lane & 15;
  const int quad = lane >> 4;
  const int blk  = blockIdx.x;
  const int t    = blk & 1;            // task (XCD parity preserved)
  const int h16  = (blk >> 1) & 7;     // h16 slice
  const int rg   = blk >> 4;           // 512-row group (0..63)
  const int h0   = h16 * 16;

  // ---- prefetch tile 0 of x (this wave's K-half, raw f32) ----
  const float* xb = x + ((size_t)rg * 512 + col) * 256 + w * 128 + quad * 8;
  uint4 pr[8];
  #pragma unroll
  for (int ks = 0; ks < 4; ++ks) {
    pr[2 * ks]     = *(const uint4*)(xb + ks * 32);
    pr[2 * ks + 1] = *(const uint4*)(xb + ks * 32 + 4);
  }

  // ---- resident expert B-fragments: 8 slots x 4 ks (this K-half) -> AGPR ----
  short8 wf[8][4];
  #pragma unroll
  for (int sr = 0; sr < 8; ++sr) {
    const int e = slot2e(sr, t);
    const unsigned short* p = WT + ((size_t)(e * 8 + h16) * 8 + w * 4) * 512
                            + (size_t)lane * 8;
    #pragma unroll
    for (int ks = 0; ks < 4; ++ks) {
      wf[sr][ks] = *(const short8*)(p + (size_t)ks * 512);
      asm volatile("" : "+a"(wf[sr][ks]));   // pin to AGPR (proven)
    }
  }

  // ---- gate B-fragments for this K-half ----
  short8 Bg[4];
  {
    const unsigned short* bp = WT + WF_GOFF_US
                             + (size_t)(t * 8 + (col & 7)) * 256
                             + (w * 4) * 32 + quad * 8;
    #pragma unroll
    for (int ks = 0; ks < 4; ++ks) Bg[ks] = *(const short8*)(bp + ks * 32);
  }
  const float bg = b_gate[t * 8 + (col & 7)];

  // ---- biases -> LDS [slot][col] (visible after tile-0 barrier) ----
  {
    int sr = tid >> 4, c = tid & 15;
    biasL[sr][c] = (sr < 4) ? b_share[sr * 128 + h0 + c]
                            : b_task[(size_t)(t * 4 + (sr - 4)) * 128 + h0 + c];
  }

  float* ob = out + ((size_t)t << 22)
            + ((size_t)rg * 512 + quad * 4) * 128 + h0 + col;

  // ---- 32 m-tiles of 16 rows; 1 barrier/tile, roles alternate ----
  #pragma unroll 1
  for (int mi = 0; mi < 32; ++mi) {
    // convert prefetched raws -> A fragments (proven RNE f2bf)
    short8 A[4];
    #pragma unroll
    for (int ks = 0; ks < 4; ++ks) {
      float4v u = __builtin_bit_cast(float4v, pr[2 * ks]);
      float4v v = __builtin_bit_cast(float4v, pr[2 * ks + 1]);
      short8 fr;
      fr[0] = (short)f2bf(u[0]); fr[1] = (short)f2bf(u[1]);
      fr[2] = (short)f2bf(u[2]); fr[3] = (short)f2bf(u[3]);
      fr[4] = (short)f2bf(v[0]); fr[5] = (short)f2bf(v[1]);
      fr[6] = (short)f2bf(v[2]); fr[7] = (short)f2bf(v[3]);
      A[ks] = fr;
    }
    // issue next tile's loads (depth-1 prefetch)
    if (mi < 31) {
      const float* xn = xb + (size_t)(mi + 1) * (16 * 256);
      #pragma unroll
      for (int ks = 0; ks < 4; ++ks) {
        pr[2 * ks]     = *(const uint4*)(xn + ks * 32);
        pr[2 * ks + 1] = *(const uint4*)(xn + ks * 32 + 4);
      }
    }

    // partial MFMAs: 9 interleaved chains (gate + 8 slots) x 4 ks
    float4v acc[8];
    #pragma unroll
    for (int i = 0; i < 8; ++i) acc[i] = (float4v){0.f, 0.f, 0.f, 0.f};
    float4v ag = {0.f, 0.f, 0.f, 0.f};
    #pragma unroll
    for (int ks = 0; ks < 4; ++ks) {
      ag     = __builtin_amdgcn_mfma_f32_16x16x32_bf16(A[ks], Bg[ks],     ag,     0, 0, 0);
      acc[0] = __builtin_amdgcn_mfma_f32_16x16x32_bf16(A[ks], wf[0][ks], acc[0], 0, 0, 0);
      acc[1] = __builtin_amdgcn_mfma_f32_16x16x32_bf16(A[ks], wf[1][ks], acc[1], 0, 0, 0);
      acc[2] = __builtin_amdgcn_mfma_f32_16x16x32_bf16(A[ks], wf[2][ks], acc[2], 0, 0, 0);
      acc[3] = __builtin_amdgcn_mfma_f32_16x16x32_bf16(A[ks], wf[3][ks], acc[3], 0, 0, 0);
      acc[4] = __builtin_amdgcn_mfma_f32_16x16x32_bf16(A[ks], wf[4][ks], acc[4], 0, 0, 0);
      acc[5] = __builtin_amdgcn_mfma_f32_16x16x32_bf16(A[ks], wf[5][ks], acc[5], 0, 0, 0);
      acc[6] = __builtin_amdgcn_mfma_f32_16x16x32_bf16(A[ks], wf[6][ks], acc[6], 0, 0, 0);
      acc[7] = __builtin_amdgcn_mfma_f32_16x16x32_bf16(A[ks], wf[7][ks], acc[7], 0, 0, 0);
    }

    const int bi = mi & 1;
    if (((mi & 1) ^ w) != 0) {
      // ---- writer: publish partials, release barrier, run ahead ----
      *(float4v*)&exch[bi][8][lane][0] = ag;
      #pragma unroll
      for (int sr = 0; sr < 8; ++sr)
        *(float4v*)&exch[bi][sr][lane][0] = acc[sr];
      __syncthreads();
    } else {
      // ---- combiner ----
      __syncthreads();
      {
        float4v o = *(const float4v*)&exch[bi][8][lane][0];
        ag += o;
      }
      #pragma unroll
      for (int sr = 0; sr < 8; ++sr) {
        float4v o = *(const float4v*)&exch[bi][sr][lane][0];
        acc[sr] += o;
      }
      // softmax over the 8 gate cols (cols 8..15 duplicate 0..7)
      float ps[4];
      #pragma unroll
      for (int r = 0; r < 4; ++r) {
        float vlog = ag[r] + bg;
        float m = vlog;
        m = fmaxf(m, __shfl_xor(m, 1));
        m = fmaxf(m, __shfl_xor(m, 2));
        m = fmaxf(m, __shfl_xor(m, 4));
        float pe = __expf(vlog - m);
        float ss = pe;
        ss += __shfl_xor(ss, 1);
        ss += __shfl_xor(ss, 2);
        ss += __shfl_xor(ss, 4);
        ps[r] = pe / ss;
      }
      if (col < 8) {
        float4 gv = {ps[0], ps[1], ps[2], ps[3]};
        *(float4*)&gw[bi][col][quad * 4] = gv;   // same-wave readers only
      }
      // epilogue: bias + relu + gated sum, nt store (16 rows x 16 cols)
      float ow[4] = {0.f, 0.f, 0.f, 0.f};
      #pragma unroll
      for (int sr = 0; sr < 8; ++sr) {
        float4 gv = *(const float4*)&gw[bi][sr][quad * 4];   // broadcast
        float bias = biasL[sr][col];
        #pragma unroll
        for (int r = 0; r < 4; ++r) {
          float vv = fmaxf(acc[sr][r] + bias, 0.f);
          ow[r] += ((const float*)&gv)[r] * vv;
        }
      }
      float* op = ob + (size_t)mi * (16 * 128);
      #pragma unroll
      for (int r = 0; r < 4; ++r)
        __builtin_nontemporal_store(ow[r], op + r * 128);
    }
  }
}

// ---------------------------------------------------------------------------
extern "C" void kernel_launch(void* const* d_in, const int* in_sizes, int n_in,
                              void* d_out, int out_size, void* d_ws, size_t ws_size,
                              hipStream_t stream) {
  const float* x       = (const float*)d_in[0];
  const float* W_share = (const float*)d_in[1];
  const float* b_share = (const float*)d_in[2];
  const float* W_task  = (const float*)d_in[3];
  const float* b_task  = (const float*)d_in[4];
  const float* W_gate  = (const float*)d_in[5];
  const float* b_gate  = (const float*)d_in[6];
  float* out = (float*)d_out;
  unsigned short* WT = (unsigned short*)d_ws;

  prep_kernel<<<97, 256, 0, stream>>>(W_share, W_task, W_gate, WT);
  dmoe_main<<<1024, 128, 0, stream>>>(x, WT, b_share, b_task, b_gate, out);
}

// Round 7
// 177.201 us; speedup vs baseline: 1.5993x; 1.5993x over previous
//
#include <hip/hip_runtime.h>

// DMoE (PLE/CGC) fused kernel for MI355X (gfx950).
// B=32768, D_IN=256, H=128, N_TASK=2, N_EXP=4, N_SHARE=4.
//
// R14: recombination of the session's proven pieces.
//  Scoreboard: R7 76.7us (8w/512thr, 1 barrier group/CU, mg4 -> 4x LDS B
//  re-read); R11 93 (4w, 2-3 groups/CU but 2x B re-read + 4x x re-read);
//  R13 209 (16x x re-read -> 264MB fetch; serial combiner).
//  R14 geometry fixes all three costs at once:
//   - 256-thr block = 32 rows x FULL 128 h x one task; 4 waves = 4 h32
//     slices (mg=1): each LDS B fragment read by exactly ONE wave, and
//     x is read exactly once per task (2x total).
//   - LDS 70.8 KB -> 2 independent blocks/CU: one block's barrier drain is
//     covered by the other block's compute (the TLP R7 lacked).
//   - A[2][8] AGPR-pinned (R9-proven), global_load_lds staging on the
//     unpadded XOR-swizzled weight image (R9-proven correct): ~100 VGPR +
//     64 AGPR at __launch_bounds__(256,2) -> no spill (WRITE tripwire).
//   - gates computed redundantly by all 4 waves (A resident), wave 0 writes.
// prep_kernel verbatim R9 (swizzled fragment image + gate table, NC copies).

typedef __attribute__((ext_vector_type(8))) short short8;   // 8 x bf16
typedef __attribute__((ext_vector_type(4))) float float4v;  // MFMA C/D

#define ROW_US     128        // 128 data bf16 (no pad; swizzle handles banks)
#define ROW_B      256
#define UNIT_US    16384      // 128 h-rows x 128 k (half-expert)
#define UNIT_B     32768
#define WGT_OFF_US 393216     // 24 * 16384
#define COPY_US    397312     // + 16*256 gate ushorts
#define COPY_B     794624

__device__ __forceinline__ unsigned short f2bf(float f) {
  unsigned u = __builtin_bit_cast(unsigned, f);
  u += 0x7FFFu + ((u >> 16) & 1u);   // round-to-nearest-even
  return (unsigned short)(u >> 16);
}

__device__ __forceinline__ int slot2e(int sr, int t) {
  return (sr < 4) ? sr : 4 + t * 4 + (sr - 4);
}

// global -> LDS direct DMA. LDS dest is wave-uniform; HW adds lane*size.
typedef const __attribute__((address_space(1))) unsigned int GBUF;
typedef __attribute__((address_space(3))) unsigned int LBUF;
__device__ __forceinline__ void gll16(const void* g, void* l) {
  __builtin_amdgcn_global_load_lds((GBUF*)g, (LBUF*)l, 16, 0, 0);
}

// ---------------------------------------------------------------------------
// Prep: WT[c][unit] images, 128h x 128k bf16 per unit, k-bytes XOR-swizzled
// by ((h&7)<<4) so main-kernel ds_read_b128 is bank-spread.
// + WgT[16][256] gate weights per copy. (verbatim R9 - proven correct)
__global__ __launch_bounds__(256)
void prep_kernel(const float* __restrict__ Ws,
                 const float* __restrict__ Wt,
                 const float* __restrict__ Wg,
                 unsigned short* __restrict__ WT, int NC) {
  int bid = blockIdx.x;
  int tid = threadIdx.x;
  if (bid < 96) {
    __shared__ float tile[64][65];
    int e  = bid >> 3;
    int kt = (bid >> 1) & 3;   // 64-wide k tile; unit k-half = kt&1
    int ht = bid & 1;          // h half
    const float* src = (e < 4) ? Ws + ((size_t)e << 15)
                               : Wt + ((size_t)(e - 4) << 15);
    int m = tid & 15, n = tid >> 4;
    #pragma unroll
    for (int i = 0; i < 4; ++i) {   // coalesced read of src[k][h]
      int kl = i * 16 + n;
      float4 v = *(const float4*)&src[(size_t)(kt * 64 + kl) * 128 + ht * 64 + m * 4];
      tile[kl][m * 4 + 0] = v.x;
      tile[kl][m * 4 + 1] = v.y;
      tile[kl][m * 4 + 2] = v.z;
      tile[kl][m * 4 + 3] = v.w;
    }
    __syncthreads();
    #pragma unroll
    for (int i = 0; i < 4; ++i) {
      int hl = i * 16 + n;
      ushort4 o;
      o.x = f2bf(tile[m * 4 + 0][hl]);
      o.y = f2bf(tile[m * 4 + 1][hl]);
      o.z = f2bf(tile[m * 4 + 2][hl]);
      o.w = f2bf(tile[m * 4 + 3][hl]);
      // k-offset within row (ushorts), XOR-swizzled: byte ^= (h&7)<<4
      int kofs = (((kt & 1) * 64) + m * 4) ^ ((hl & 7) << 3);
      size_t base = (size_t)(e * 2 + (kt >> 1)) * UNIT_US
                  + (size_t)(ht * 64 + hl) * ROW_US + kofs;
      for (int c = 0; c < NC; ++c)
        *(ushort4*)&WT[(size_t)c * COPY_US + base] = o;
    }
  } else {
    // gate weights WgT[n][256], n = t*8+g
    #pragma unroll
    for (int it = 0; it < 16; ++it) {
      int j = it * 256 + tid;
      int n = j >> 8, k = j & 255;
      int t = n >> 3, g = n & 7;
      unsigned short v = f2bf(Wg[(size_t)(t * 256 + k) * 8 + g]);
      for (int c = 0; c < NC; ++c)
        WT[(size_t)c * COPY_US + WGT_OFF_US + j] = v;
    }
  }
}

// ---------------------------------------------------------------------------
__global__ __launch_bounds__(256, 2)
void dmoe_main(const float* __restrict__ x,
               const unsigned short* __restrict__ WT,
               const float* __restrict__ b_share,
               const float* __restrict__ b_task,
               const float* __restrict__ b_gate,
               float* __restrict__ out, int NC) {
  __shared__ unsigned short Bs0[UNIT_US];   // 32768 B
  __shared__ unsigned short Bs1[UNIT_US];   // 32768 B
  __shared__ float gatesL[8 * 36];          // [gate-col][32 rows + pad]
  __shared__ float biasLds[8 * 128];        // slot-indexed, full h

  const int tid  = threadIdx.x;
  const int lane = tid & 63;
  const int w    = tid >> 6;    // wave 0..3 = h32 slice (mg = 1)
  const int col  = lane & 15;
  const int quad = lane >> 4;
  const int blk  = blockIdx.x;
  const int t    = blk & 1;     // task (== XCD parity: one task per XCD)
  const int rt   = blk >> 1;    // row tile (32 rows), 1024 tiles
  const int rot  = (blk >> 3) & 7;

  const char* WTc = (const char*)WT + (size_t)((blk >> 3) % NC) * COPY_B;

  // ---- DMA staging: this wave's linear 8192-B chunk of one unit ----
  auto stage = [&](int un, unsigned short* dst) {
    const char* g = WTc + (size_t)un * UNIT_B + w * 8192;
    char* l = (char*)dst + w * 8192;          // wave-uniform LDS base
    #pragma unroll
    for (int i = 0; i < 8; ++i)
      gll16(g + i * 1024 + lane * 16, l + i * 1024);
  };

  // ---- issue first unit's loads first (longest latency) ----
  const int e0 = slot2e(rot, t);
  stage(e0 * 2, Bs0);

  // ---- A-fragments: 2 m-tiles x 8 k-steps resident; pin into AGPRs ----
  short8 A[2][8];
  {
    const float* xb = x + ((size_t)rt * 32 + col) * 256 + quad * 8;
    #pragma unroll
    for (int mt = 0; mt < 2; ++mt) {
      const float* xr = xb + (size_t)mt * 16 * 256;
      #pragma unroll
      for (int k = 0; k < 8; ++k) {
        float4v u = *(const float4v*)(xr + k * 32);
        float4v v = *(const float4v*)(xr + k * 32 + 4);
        short8 fr;
        fr[0] = (short)f2bf(u[0]); fr[1] = (short)f2bf(u[1]);
        fr[2] = (short)f2bf(u[2]); fr[3] = (short)f2bf(u[3]);
        fr[4] = (short)f2bf(v[0]); fr[5] = (short)f2bf(v[1]);
        fr[6] = (short)f2bf(v[2]); fr[7] = (short)f2bf(v[3]);
        A[mt][k] = fr;
        asm volatile("" : "+a"(A[mt][k]));   // force AGPR residency (proven)
      }
    }
  }

  // ---- biases -> LDS (slot-indexed: 0..3 shared, 4..7 this task) ----
  for (int i = tid; i < 1024; i += 256) {
    int sr = i >> 7, h = i & 127;
    biasLds[i] = (sr < 4) ? b_share[sr * 128 + h]
                          : b_task[(size_t)(t * 4 + (sr - 4)) * 128 + h];
  }

  // ---- gates: all 4 waves compute redundantly (A resident); w0 writes ----
  {
    const unsigned short* WgT = (const unsigned short*)(WTc + WGT_OFF_US * 2);
    const int gr = col & 7;
    const unsigned short* bp = WgT + (size_t)(t * 8 + gr) * 256 + quad * 8;
    float bg = b_gate[t * 8 + gr];
    float4v ag[2] = {{0.f,0.f,0.f,0.f},{0.f,0.f,0.f,0.f}};
    #pragma unroll
    for (int kb = 0; kb < 2; ++kb) {           // 2 k-halves: caps reg peak
      short8 Bg[4];
      #pragma unroll
      for (int j = 0; j < 4; ++j) Bg[j] = *(const short8*)(bp + (kb * 4 + j) * 32);
      #pragma unroll
      for (int j = 0; j < 4; ++j) {
        ag[0] = __builtin_amdgcn_mfma_f32_16x16x32_bf16(A[0][kb * 4 + j], Bg[j], ag[0], 0, 0, 0);
        ag[1] = __builtin_amdgcn_mfma_f32_16x16x32_bf16(A[1][kb * 4 + j], Bg[j], ag[1], 0, 0, 0);
      }
    }
    #pragma unroll
    for (int mt = 0; mt < 2; ++mt) {
      #pragma unroll
      for (int r = 0; r < 4; ++r) {
        float vlog = ag[mt][r] + bg;
        float m = vlog;                      // softmax over 8 cols
        m = fmaxf(m, __shfl_xor(m, 1));
        m = fmaxf(m, __shfl_xor(m, 2));
        m = fmaxf(m, __shfl_xor(m, 4));
        float p = __expf(vlog - m);
        float s = p;
        s += __shfl_xor(s, 1);
        s += __shfl_xor(s, 2);
        s += __shfl_xor(s, 4);
        if (w == 0 && col < 8)
          gatesL[col * 36 + mt * 16 + quad * 4 + r] = p / s;
      }
    }
  }
  __syncthreads();   // unit 0 staged + gates/biases visible

  // ---- accumulators (task-local) ----
  float tw[2][2][4];   // [mt][nt][r]
  #pragma unroll
  for (int mt = 0; mt < 2; ++mt)
    #pragma unroll
    for (int nt = 0; nt < 2; ++nt)
      #pragma unroll
      for (int r = 0; r < 4; ++r)
        tw[mt][nt][r] = 0.f;

  const int hb = w * 32;           // this wave's h32 slice
  const int c7 = col & 7;
  float4v acc[2][2];

  // ---- slot loop: 8 experts x 2 k-halves; buffer parity = kh ----
  #pragma unroll 1
  for (int s = 0; s < 8; ++s) {
    const int sr  = (s + rot) & 7;
    const int e   = slot2e(sr, t);
    const int e2  = slot2e((s + 1 + rot) & 7, t);
    #pragma unroll
    for (int kh = 0; kh < 2; ++kh) {
      const bool doStage = !(s == 7 && kh == 1);
      if (doStage) stage(kh == 0 ? e * 2 + 1 : e2 * 2, kh ? Bs0 : Bs1);
      if (kh == 0) {
        #pragma unroll
        for (int mt = 0; mt < 2; ++mt)
          #pragma unroll
          for (int nt = 0; nt < 2; ++nt)
            acc[mt][nt] = (float4v){0.f, 0.f, 0.f, 0.f};
      }
      // compute this unit from Bs[kh]
      {
        const char* Bb = (const char*)(kh ? Bs1 : Bs0);
        __builtin_amdgcn_s_setprio(1);
        #pragma unroll
        for (int kk = 0; kk < 4; ++kk) {
          #pragma unroll
          for (int nt = 0; nt < 2; ++nt) {
            short8 bfr = *(const short8*)(Bb + (hb + nt * 16 + col) * ROW_B
                                          + ((((kk << 2) + quad) ^ c7) << 4));
            acc[0][nt] = __builtin_amdgcn_mfma_f32_16x16x32_bf16(
                A[0][kh * 4 + kk], bfr, acc[0][nt], 0, 0, 0);
            acc[1][nt] = __builtin_amdgcn_mfma_f32_16x16x32_bf16(
                A[1][kh * 4 + kk], bfr, acc[1][nt], 0, 0, 0);
          }
        }
        __builtin_amdgcn_s_setprio(0);
      }
      // epilogue after second half
      if (kh == 1) {
        #pragma unroll
        for (int mt = 0; mt < 2; ++mt) {
          float4 g = *(const float4*)&gatesL[sr * 36 + mt * 16 + quad * 4];
          #pragma unroll
          for (int nt = 0; nt < 2; ++nt) {
            float bias = biasLds[sr * 128 + hb + nt * 16 + col];
            #pragma unroll
            for (int r = 0; r < 4; ++r) {
              float v = fmaxf(acc[mt][nt][r] + bias, 0.f);
              tw[mt][nt][r] += ((const float*)&g)[r] * v;
            }
          }
        }
      }
      __syncthreads();
    }
  }

  // ---- write towers (nontemporal): out[t][row][h] ----
  #pragma unroll
  for (int mt = 0; mt < 2; ++mt)
    #pragma unroll
    for (int r = 0; r < 4; ++r) {
      size_t row = (size_t)rt * 32 + mt * 16 + quad * 4 + r;
      float* op = out + ((size_t)t << 22) + row * 128 + hb;
      #pragma unroll
      for (int nt = 0; nt < 2; ++nt)
        __builtin_nontemporal_store(tw[mt][nt][r], op + nt * 16 + col);
    }
}

// ---------------------------------------------------------------------------
extern "C" void kernel_launch(void* const* d_in, const int* in_sizes, int n_in,
                              void* d_out, int out_size, void* d_ws, size_t ws_size,
                              hipStream_t stream) {
  const float* x       = (const float*)d_in[0];
  const float* W_share = (const float*)d_in[1];
  const float* b_share = (const float*)d_in[2];
  const float* W_task  = (const float*)d_in[3];
  const float* b_task  = (const float*)d_in[4];
  const float* W_gate  = (const float*)d_in[5];
  const float* b_gate  = (const float*)d_in[6];
  float* out = (float*)d_out;
  unsigned short* WT = (unsigned short*)d_ws;

  int NC = (int)(ws_size / (size_t)COPY_B);
  if (NC < 1) NC = 1;
  if (NC > 2) NC = 2;

  prep_kernel<<<97, 256, 0, stream>>>(W_share, W_task, W_gate, WT, NC);
  dmoe_main<<<2048, 256, 0, stream>>>(x, WT, b_share, b_task, b_gate, out, NC);
}